// Round 1
// baseline (96.286 us; speedup 1.0000x reference)
//
#include <hip/hip_runtime.h>

// SGNN projection: out[b,h] = (sum_m centered(abs(sig[p,b,m]*seed[h]) % B) * mask) / count[p,b] / HALF
// B = 2^31 - 1 (Mersenne prime) -> modulo via fold: x mod M == fold(hi31 + lo31) since 2^31 == 1 (mod M).
// Partitions p: h<112 -> 0, h<336 -> 1, else 2. Seed index == global h.

#define BCONST 2147483647u   // 2^31 - 1
#define HALF_B 1073741823u   // BCONST >> 1

__global__ __launch_bounds__(256) void sgnn_project_kernel(
    const int* __restrict__ sig,    // [3, B, 128] int32 (values < 2^31)
    const int* __restrict__ mask,   // [3, B, 128] int32 0/1
    const int* __restrict__ seeds,  // [672] int32
    float* __restrict__ out,        // [B, 672] fp32
    int nbatch)
{
    __shared__ unsigned int slds[384];  // 3 partitions x 128 slots, masked sigs
    __shared__ int cnt[3];
    const int b   = blockIdx.x;
    const int tid = threadIdx.x;

    if (tid < 3) cnt[tid] = 0;
    __syncthreads();

    // Stage masked signatures into LDS; count valid slots per partition.
    // Zeroed slots contribute exactly 0 downstream (0*seed % B = 0, centered 0),
    // so the inner loop needs no mask.
    for (int e = tid; e < 384; e += 256) {
        const int p = e >> 7;
        const int m = e & 127;
        const int gidx = (p * nbatch + b) * 128 + m;
        const int mk = mask[gidx];
        slds[e] = mk ? (unsigned int)sig[gidx] : 0u;
        if (mk) atomicAdd(&cnt[p], 1);
    }
    __syncthreads();

    for (int h = tid; h < 672; h += 256) {
        const int p = (h < 112) ? 0 : ((h < 336) ? 1 : 2);
        const unsigned long long seed = (unsigned long long)(unsigned int)seeds[h];
        const unsigned int* sp = &slds[p << 7];

        long long acc = 0;  // exact: |sum| < 128 * 2^30 = 2^37
        #pragma unroll 8
        for (int m = 0; m < 128; ++m) {
            const unsigned long long prod = (unsigned long long)sp[m] * seed;  // < 2^62
            // fold twice: x mod (2^31-1)
            const unsigned long long s = (prod >> 31) + (prod & 0x7FFFFFFFULL);  // < 2^32
            unsigned int t = (unsigned int)(s >> 31) + ((unsigned int)s & 0x7FFFFFFFu);  // <= M+1
            if (t >= BCONST) t -= BCONST;
            // center to [-HALF, HALF]: unsigned wrap then signed reinterpret is exact
            const int c = (t > HALF_B) ? (int)(t - BCONST) : (int)t;
            acc += (long long)c;
        }

        int cn = cnt[p];
        if (cn < 1) cn = 1;
        // 1/HALF rounds to exactly 2^-30 in fp32, so * is bit-identical to the ref's /
        out[b * 672 + h] = ((float)acc / (float)cn) * (1.0f / 1073741823.0f);
    }
}

extern "C" void kernel_launch(void* const* d_in, const int* in_sizes, int n_in,
                              void* d_out, int out_size, void* d_ws, size_t ws_size,
                              hipStream_t stream) {
    const int* sig   = (const int*)d_in[0];  // signatures [3, B, 128]
    const int* mask  = (const int*)d_in[1];  // mask       [3, B, 128]
    const int* seeds = (const int*)d_in[2];  // hash_seed  [672]
    float* out = (float*)d_out;

    const int nbatch = in_sizes[0] / (3 * 128);  // 1024
    sgnn_project_kernel<<<dim3(nbatch), dim3(256), 0, stream>>>(sig, mask, seeds, out, nbatch);
}

// Round 2
// 90.317 us; speedup vs baseline: 1.0661x; 1.0661x over previous
//
#include <hip/hip_runtime.h>

// SGNN projection, VALU-optimized.
// Math: out[b,h] = (1/HALF) * mean_m( centered( (sig*seed) mod M ) ), M = 2^31-1 (Mersenne).
// Trick 1: centered(v) = ((v + HALF) mod M) - HALF, so prod2 = sig*seed + HALF (one v_mad_u64_u32)
//          and masked slots (sig=0 -> residue HALF) contribute exactly 0 after the linear -HALF,
//          which hoists to a single -n*HALF outside the loop.
// Trick 2: one Mersenne fold: s = (prod2>>31) + (prod2 & 0x7FFFFFFF) < 2^32, s == prod2 (mod M).
//          Accumulate sum(s) in 64-bit + quotient count q = [s>=M] + [s>=2M]; residue sum = sum - M*q.
// Split each batch row's m-range over 2 blocks (grid 2048 -> 32 waves/CU) and combine with one
// float atomicAdd per output (d_out zeroed via hipMemsetAsync).

#define M31    2147483647u   // 2^31 - 1
#define HALF_B 1073741823u   // (M31-1)/2 = 2^30 - 1

__global__ __launch_bounds__(256) void sgnn_project_kernel(
    const int* __restrict__ sig,    // [3, B, 128]
    const int* __restrict__ mask,   // [3, B, 128]
    const int* __restrict__ seeds,  // [672]
    float* __restrict__ out,        // [B, 672], pre-zeroed
    int nbatch)
{
    __shared__ unsigned ssig[192];  // 3 partitions x 64 (this block's m-half), mask-zeroed
    __shared__ int scnt[3];         // full-row valid counts
    const int tid  = threadIdx.x;
    const int b    = blockIdx.x >> 1;
    const int half = blockIdx.x & 1;

    if (tid < 3) scnt[tid] = 0;
    __syncthreads();

    // Full-row mask counts via per-wave ballot (partitions are 128-aligned, so each
    // 64-lane segment is partition-uniform). 6 LDS atomics per block total.
    {
        int e = tid;                                  // [0,256): partitions 0,1
        int p = e >> 7;
        int g = (p * nbatch + b) * 128 + (e & 127);
        unsigned long long bal = __ballot(mask[g] != 0);
        if ((tid & 63) == 0) atomicAdd(&scnt[p], (int)__popcll(bal));
        if (tid < 128) {                              // wave-uniform branch (waves 0,1 only)
            e = 256 + tid;                            // [256,384): partition 2
            g = (2 * nbatch + b) * 128 + (e & 127);
            bal = __ballot(mask[g] != 0);
            if ((tid & 63) == 0) atomicAdd(&scnt[2], (int)__popcll(bal));
        }
    }

    // Stage this block's m-half of each partition into LDS, mask-zeroed.
    if (tid < 192) {
        const int p = tid >> 6, j = tid & 63;
        const int g = (p * nbatch + b) * 128 + half * 64 + j;
        ssig[tid] = mask[g] ? (unsigned)sig[g] : 0u;
    }
    __syncthreads();

    float invc[3];
    #pragma unroll
    for (int p = 0; p < 3; ++p) {
        int c = scnt[p]; if (c < 1) c = 1;
        invc[p] = 1.0f / ((float)c * 1073741823.0f);
    }

    for (int h = tid; h < 672; h += 256) {
        const int p = (h < 112) ? 0 : (h < 336) ? 1 : 2;
        const unsigned* sp = &ssig[p << 6];
        const unsigned long long seed = (unsigned long long)(unsigned)seeds[h];

        unsigned long long sum = 0;   // sum of s < 2^32 each, 64 iters -> < 2^38, exact
        unsigned q = 0;               // Mersenne quotient count
        #pragma unroll
        for (int mm = 0; mm < 64; mm += 4) {
            const uint4 sv = *(const uint4*)&sp[mm];
            const unsigned vv[4] = {sv.x, sv.y, sv.z, sv.w};
            #pragma unroll
            for (int j = 0; j < 4; ++j) {
                const unsigned long long p2 =
                    (unsigned long long)vv[j] * seed + (unsigned long long)HALF_B; // mad_u64_u32
                const unsigned lo = (unsigned)p2;
                const unsigned a1 = (unsigned)(p2 >> 31);      // alignbit(hi,lo,31); < 2^31
                const unsigned s  = a1 + (lo & 0x7FFFFFFFu);   // <= 2^32-2, == p2 (mod M)
                q += (s >= M31);
                q += (s >= 0xFFFFFFFEu);                       // s >= 2M (rare but exact)
                sum += s;
            }
        }
        // exact centered sum over this m-half: residues in [0,M), minus HALF per element
        const long long centered = (long long)sum
                                 - (long long)q * (long long)M31
                                 - 64LL * (long long)HALF_B;
        atomicAdd(&out[b * 672 + h], (float)centered * invc[p]);
    }
}

extern "C" void kernel_launch(void* const* d_in, const int* in_sizes, int n_in,
                              void* d_out, int out_size, void* d_ws, size_t ws_size,
                              hipStream_t stream) {
    const int* sig   = (const int*)d_in[0];
    const int* mask  = (const int*)d_in[1];
    const int* seeds = (const int*)d_in[2];
    float* out = (float*)d_out;

    const int nbatch = in_sizes[0] / (3 * 128);  // 1024
    hipMemsetAsync(d_out, 0, (size_t)out_size * sizeof(float), stream);
    sgnn_project_kernel<<<dim3(2 * nbatch), dim3(256), 0, stream>>>(sig, mask, seeds, out, nbatch);
}

// Round 3
// 80.097 us; speedup vs baseline: 1.2021x; 1.1276x over previous
//
#include <hip/hip_runtime.h>

// SGNN projection, round 3: lane-per-output, zero idle lanes, no LDS/atomics.
//
// Math (M = 2^31-1 Mersenne, HALF = 2^30-1):
//   centered(v) = ((v + HALF) mod M) - HALF, so p2 = sig*seed + HALF (one v_mad_u64_u32)
//   and masked slots (sig=0 -> residue HALF) contribute 0 after the linear -HALF,
//   hoisted to a single -128*HALF.
//   Fold: s = (p2>>31) + (p2 & M). Since sig,seed <= 2^31-2, s <= 2^32-4 < 2M
//   ALWAYS, so residue = s - M*[s >= M] exactly (single compare; the old >=2M
//   check was dead code). Accumulate sum(s) u64 + q = count[s>=M]; centered
//   partial = sum - M*q - 128*HALF, exact in int64.
//
// Prep kernel writes mask-zeroed sigs + 1/(cnt*HALF) into d_ws so the main
// kernel is pure compute: flat t = b*672 + h, one lane per output, loads are
// wave-broadcast (all lanes of a wave read the same row words -> 1 request).

#define M31    2147483647u   // 2^31 - 1
#define HALF_B 1073741823u   // 2^30 - 1

__global__ __launch_bounds__(64) void sgnn_prep_kernel(
    const int* __restrict__ sig,    // [3, B, 128]
    const int* __restrict__ mask,   // [3, B, 128]
    unsigned* __restrict__ msig,    // [3, B, 128] mask-zeroed
    float* __restrict__ invc)       // [3, B]  = 1/(max(cnt,1)*HALF)
{
    const int row = blockIdx.x;          // p*nbatch + b
    const int t   = threadIdx.x;
    const int g0  = row * 128 + t;
    const int g1  = g0 + 64;
    const int mk0 = mask[g0], mk1 = mask[g1];
    msig[g0] = mk0 ? (unsigned)sig[g0] : 0u;
    msig[g1] = mk1 ? (unsigned)sig[g1] : 0u;
    const unsigned long long b0 = __ballot(mk0 != 0);
    const unsigned long long b1 = __ballot(mk1 != 0);
    if (t == 0) {
        int c = __popcll(b0) + __popcll(b1);
        if (c < 1) c = 1;
        invc[row] = 1.0f / ((float)c * 1073741823.0f);
    }
}

__global__ __launch_bounds__(256, 8) void sgnn_main_kernel(
    const unsigned* __restrict__ msig,  // [3, B, 128]
    const float* __restrict__ invc,     // [3, B]
    const int* __restrict__ seeds,      // [672]
    float* __restrict__ out,            // [B, 672] == flat[t]
    int nbatch)
{
    const unsigned t = blockIdx.x * 256u + threadIdx.x;  // [0, nbatch*672), exact grid
    // b = floor(t/672) = floor((t>>5)/21), exact for t < 2^21 via magic 99865 = ceil(2^21/21)
    const unsigned x = t >> 5;
    const unsigned b = (x * 99865u) >> 21;
    const unsigned h = t - 672u * b;
    const int p = (h < 112u) ? 0 : (h < 336u) ? 1 : 2;

    const unsigned* __restrict__ rp = msig + (unsigned)(p * nbatch + b) * 128u;
    const unsigned long long seed = (unsigned long long)(unsigned)seeds[h];

    unsigned long long sum0 = 0, sum1 = 0;  // sum of s (< 2^32 each); 128 iters < 2^39
    unsigned q0 = 0, q1 = 0;                // count of s >= M

    for (int mm = 0; mm < 128; mm += 16) {
        const uint4 v0 = *(const uint4*)(rp + mm);
        const uint4 v1 = *(const uint4*)(rp + mm + 4);
        const uint4 v2 = *(const uint4*)(rp + mm + 8);
        const uint4 v3 = *(const uint4*)(rp + mm + 12);
        const unsigned vv[16] = {v0.x, v0.y, v0.z, v0.w, v1.x, v1.y, v1.z, v1.w,
                                 v2.x, v2.y, v2.z, v2.w, v3.x, v3.y, v3.z, v3.w};
        #pragma unroll
        for (int j = 0; j < 16; j += 2) {
            {
                const unsigned long long p2 =
                    (unsigned long long)vv[j] * seed + (unsigned long long)HALF_B;
                const unsigned s = (unsigned)(p2 >> 31) + ((unsigned)p2 & 0x7FFFFFFFu);
                q0 += (s >= M31);
                sum0 += s;
            }
            {
                const unsigned long long p2 =
                    (unsigned long long)vv[j + 1] * seed + (unsigned long long)HALF_B;
                const unsigned s = (unsigned)(p2 >> 31) + ((unsigned)p2 & 0x7FFFFFFFu);
                q1 += (s >= M31);
                sum1 += s;
            }
        }
    }

    const long long centered = (long long)(sum0 + sum1)
                             - (long long)(q0 + q1) * 2147483647LL
                             - 128LL * 1073741823LL;
    out[t] = (float)centered * invc[p * nbatch + b];
}

extern "C" void kernel_launch(void* const* d_in, const int* in_sizes, int n_in,
                              void* d_out, int out_size, void* d_ws, size_t ws_size,
                              hipStream_t stream) {
    const int* sig   = (const int*)d_in[0];
    const int* mask  = (const int*)d_in[1];
    const int* seeds = (const int*)d_in[2];
    float* out = (float*)d_out;

    const int nbatch = in_sizes[0] / (3 * 128);        // 1024
    unsigned* msig = (unsigned*)d_ws;                   // 3*nbatch*128 u32
    float* invc = (float*)((char*)d_ws + (size_t)(3 * nbatch * 128) * 4);  // 3*nbatch f32

    sgnn_prep_kernel<<<dim3(3 * nbatch), dim3(64), 0, stream>>>(sig, mask, msig, invc);
    const int total = nbatch * 672;                     // 688128 = 2688 * 256 exactly
    sgnn_main_kernel<<<dim3(total / 256), dim3(256), 0, stream>>>(msig, invc, seeds, out, nbatch);
}